// Round 1
// baseline (1293.499 us; speedup 1.0000x reference)
//
#include <hip/hip_runtime.h>
#include <cmath>

#define D_IN 512
#define HC   512   // H1*C1 == H2*C2 == D_IN
#define NH1  8
#define NC1  64
#define NH2  4
#define NC2  128

// ---------------- GEMM: C[M,N] = A[M,K] @ B[K,N], row-major, fp32 ----------
__global__ void k_gemm(const float* __restrict__ A, const float* __restrict__ B,
                       float* __restrict__ C, int M, int N, int K) {
  __shared__ float As[16][65];   // [k][m], padded
  __shared__ float Bs[16][64];   // [k][n]
  int tx = threadIdx.x, ty = threadIdx.y;
  int tid = ty * 16 + tx;
  int m0 = blockIdx.y * 64;
  int n0 = blockIdx.x * 64;
  float acc[4][4] = {};
  for (int k0 = 0; k0 < K; k0 += 16) {
#pragma unroll
    for (int l = 0; l < 4; ++l) {
      int idx = tid + l * 256;
      int mm = idx >> 4, kk = idx & 15;
      int gm = m0 + mm;
      As[kk][mm] = (gm < M) ? A[(size_t)gm * K + k0 + kk] : 0.0f;
    }
#pragma unroll
    for (int l = 0; l < 4; ++l) {
      int idx = tid + l * 256;
      int kk = idx >> 6, nn = idx & 63;
      Bs[kk][nn] = B[(size_t)(k0 + kk) * N + n0 + nn];
    }
    __syncthreads();
#pragma unroll
    for (int k = 0; k < 16; ++k) {
      float a[4], b[4];
#pragma unroll
      for (int i = 0; i < 4; ++i) a[i] = As[k][ty * 4 + i];
#pragma unroll
      for (int j = 0; j < 4; ++j) b[j] = Bs[k][tx * 4 + j];
#pragma unroll
      for (int i = 0; i < 4; ++i)
#pragma unroll
        for (int j = 0; j < 4; ++j) acc[i][j] += a[i] * b[j];
    }
    __syncthreads();
  }
  for (int i = 0; i < 4; ++i) {
    int gm = m0 + ty * 4 + i;
    if (gm >= M) continue;
    for (int j = 0; j < 4; ++j)
      C[(size_t)gm * N + n0 + tx * 4 + j] = acc[i][j];
  }
}

// ------------- attention scores: asrc[n,h] = <xp[n,h,:], att_src[h,:]> -----
__global__ void k_att(const float* __restrict__ xp, const float* __restrict__ att_src,
                      const float* __restrict__ att_dst, float* __restrict__ asrc,
                      float* __restrict__ adst, int N, int H, int C) {
  int idx = blockIdx.x * blockDim.x + threadIdx.x;
  if (idx >= N * H) return;
  int n = idx / H, h = idx - n * H;
  const float* xr = xp + (size_t)n * H * C + (size_t)h * C;
  const float* s = att_src + (size_t)h * C;
  const float* d = att_dst + (size_t)h * C;
  float vs = 0.f, vd = 0.f;
  for (int c = 0; c < C; ++c) { float v = xr[c]; vs += v * s[c]; vd += v * d[c]; }
  asrc[idx] = vs; adst[idx] = vd;
}

__global__ void k_fill(float* __restrict__ p, float v, int n) {
  int i = blockIdx.x * blockDim.x + threadIdx.x;
  if (i < n) p[i] = v;
}

__device__ inline void atomicMaxF(float* addr, float v) {
  unsigned int u = __float_as_uint(v);
  if (u <= 0x7FFFFFFFu) atomicMax((int*)addr, __float_as_int(v));     // v >= +0.0
  else                  atomicMin((unsigned int*)addr, u);            // v < 0 (incl -0.0)
}

// -------- edge score (leaky relu) + segment max over dst --------------------
__global__ void k_edge_score(const int* __restrict__ ei, int E, int Etot,
                             const float* __restrict__ asrc, const float* __restrict__ adst,
                             float* __restrict__ esc, float* __restrict__ m, int H) {
  int idx = blockIdx.x * blockDim.x + threadIdx.x;
  if (idx >= Etot * H) return;
  int e = idx / H, h = idx - e * H;
  int s = (e < E) ? ei[e] : e - E;
  int d = (e < E) ? ei[E + e] : e - E;
  float v = asrc[s * H + h] + adst[d * H + h];
  v = (v > 0.f) ? v : 0.2f * v;
  esc[idx] = v;
  atomicMaxF(&m[d * H + h], v);
}

// -------- exp(e - m[dst]) + segment sum ------------------------------------
__global__ void k_edge_exp(const int* __restrict__ ei, int E, int Etot,
                           const float* __restrict__ m, float* __restrict__ esc,
                           float* __restrict__ den, int H) {
  int idx = blockIdx.x * blockDim.x + threadIdx.x;
  if (idx >= Etot * H) return;
  int e = idx / H, h = idx - e * H;
  int d = (e < E) ? ei[E + e] : e - E;
  float ex = expf(esc[idx] - m[d * H + h]);
  esc[idx] = ex;
  atomicAdd(&den[d * H + h], ex);
}

// -------- alpha = ex / (den[dst] + 1e-16) ----------------------------------
__global__ void k_alpha(const int* __restrict__ ei, int E, int Etot,
                        const float* __restrict__ den, float* __restrict__ esc, int H) {
  int idx = blockIdx.x * blockDim.x + threadIdx.x;
  if (idx >= Etot * H) return;
  int e = idx / H, h = idx - e * H;
  int d = (e < E) ? ei[E + e] : e - E;
  esc[idx] = esc[idx] / (den[d * H + h] + 1e-16f);
}

// -------- out[dst,h,c] += alpha[e,h] * xp[src,h,c] -------------------------
__global__ void k_agg(const int* __restrict__ ei, int E, int Etot,
                      const float* __restrict__ alpha, const float* __restrict__ xp,
                      float* __restrict__ outb, int H, int C) {
  long long idx = (long long)blockIdx.x * blockDim.x + threadIdx.x;
  int hc_dim = H * C;
  long long total = (long long)Etot * hc_dim;
  if (idx >= total) return;
  int e = (int)(idx / hc_dim);
  int hc = (int)(idx - (long long)e * hc_dim);
  int h = hc / C;
  int s = (e < E) ? ei[e] : e - E;
  int d = (e < E) ? ei[E + e] : e - E;
  float a = alpha[e * H + h];
  atomicAdd(&outb[(size_t)d * hc_dim + hc], a * xp[(size_t)s * hc_dim + hc]);
}

// -------- h = elu(x + b) in place ------------------------------------------
__global__ void k_elu(float* __restrict__ buf, const float* __restrict__ b, int total) {
  int idx = blockIdx.x * blockDim.x + threadIdx.x;
  if (idx >= total) return;
  float v = buf[idx] + b[idx & (HC - 1)];
  buf[idx] = (v > 0.f) ? v : expm1f(v);
}

// -------- mean over heads + bias -> d_out+1 --------------------------------
__global__ void k_mean(const float* __restrict__ agg, const float* __restrict__ b2,
                       float* __restrict__ out, int N) {
  int idx = blockIdx.x * blockDim.x + threadIdx.x;
  if (idx >= N * NC2) return;
  int n = idx / NC2, c = idx - n * NC2;
  float s = 0.f;
#pragma unroll
  for (int h = 0; h < NH2; ++h) s += agg[(size_t)n * HC + h * NC2 + c];
  out[idx] = s * (1.0f / NH2) + b2[c];
}

// -------- CE loss: one wave per node ---------------------------------------
__global__ void k_loss(const float* __restrict__ out, const int* __restrict__ y,
                       const int* __restrict__ msk, float* __restrict__ acc, int N) {
  int gtid = blockIdx.x * blockDim.x + threadIdx.x;
  int wave = gtid >> 6;
  int lane = gtid & 63;
  if (wave >= N) return;
  const float* row = out + (size_t)wave * NC2;
  float v0 = row[lane], v1 = row[lane + 64];
  float mx = fmaxf(v0, v1);
#pragma unroll
  for (int o = 32; o > 0; o >>= 1) mx = fmaxf(mx, __shfl_xor(mx, o));
  float se = expf(v0 - mx) + expf(v1 - mx);
#pragma unroll
  for (int o = 32; o > 0; o >>= 1) se += __shfl_xor(se, o);
  if (lane == 0 && msk[wave] != 0) {
    float lse = mx + logf(se);
    float ce = lse - row[y[wave]];
    atomicAdd(&acc[0], ce);
    atomicAdd(&acc[1], 1.0f);
  }
}

__global__ void k_final(const float* __restrict__ acc, float* __restrict__ out0) {
  if (threadIdx.x == 0 && blockIdx.x == 0) out0[0] = acc[0] / acc[1];
}

extern "C" void kernel_launch(void* const* d_in, const int* in_sizes, int n_in,
                              void* d_out, int out_size, void* d_ws, size_t ws_size,
                              hipStream_t stream) {
  const float* x   = (const float*)d_in[0];
  const int*   ei  = (const int*)d_in[1];
  const int*   y   = (const int*)d_in[2];
  const int*   msk = (const int*)d_in[3];
  const float* W1  = (const float*)d_in[4];
  const float* as1 = (const float*)d_in[5];
  const float* ad1 = (const float*)d_in[6];
  const float* b1  = (const float*)d_in[7];
  const float* W2  = (const float*)d_in[8];
  const float* as2 = (const float*)d_in[9];
  const float* ad2 = (const float*)d_in[10];
  const float* b2  = (const float*)d_in[11];
  float* out = (float*)d_out;

  int N = in_sizes[0] / D_IN;   // 20000
  int E = in_sizes[1] / 2;      // 100000
  int Etot = E + N;             // 120000 (self-loops appended)

  float* ws = (float*)d_ws;
  size_t NF = (size_t)N * HC;
  float* xp   = ws;             // xp1, later xp2         (N*512)
  float* agg  = xp + NF;        // agg1/h1, later agg2    (N*512)
  float* asr1 = agg + NF;
  float* adt1 = asr1 + (size_t)N * NH1;
  float* asr2 = adt1 + (size_t)N * NH1;
  float* adt2 = asr2 + (size_t)N * NH2;
  float* m1   = adt2 + (size_t)N * NH2;   // m1,m2 contiguous (-inf fill)
  float* m2   = m1 + (size_t)N * NH1;
  float* den1 = m2 + (size_t)N * NH2;     // den1,den2,acc contiguous (zero fill)
  float* den2 = den1 + (size_t)N * NH1;
  float* acc  = den2 + (size_t)N * NH2;
  float* esc1 = acc + 2;
  float* esc2 = esc1 + (size_t)Etot * NH1;

  dim3 gblk(16, 16);
  dim3 ggrid(HC / 64, (N + 63) / 64);

  // init
  {
    int nfill = N * (NH1 + NH2);
    k_fill<<<(nfill + 255) / 256, 256, 0, stream>>>(m1, -INFINITY, nfill);
    hipMemsetAsync(den1, 0, ((size_t)N * (NH1 + NH2) + 2) * sizeof(float), stream);
    hipMemsetAsync(agg, 0, NF * sizeof(float), stream);
  }

  // ---- layer 1 ----
  k_gemm<<<ggrid, gblk, 0, stream>>>(x, W1, xp, N, HC, D_IN);
  k_att<<<(N * NH1 + 255) / 256, 256, 0, stream>>>(xp, as1, ad1, asr1, adt1, N, NH1, NC1);
  k_edge_score<<<(Etot * NH1 + 255) / 256, 256, 0, stream>>>(ei, E, Etot, asr1, adt1, esc1, m1, NH1);
  k_edge_exp<<<(Etot * NH1 + 255) / 256, 256, 0, stream>>>(ei, E, Etot, m1, esc1, den1, NH1);
  k_alpha<<<(Etot * NH1 + 255) / 256, 256, 0, stream>>>(ei, E, Etot, den1, esc1, NH1);
  {
    long long total = (long long)Etot * HC;
    k_agg<<<(int)((total + 255) / 256), 256, 0, stream>>>(ei, E, Etot, esc1, xp, agg, NH1, NC1);
  }
  k_elu<<<(int)((NF + 255) / 256), 256, 0, stream>>>(agg, b1, (int)NF);

  // ---- layer 2 ----
  k_gemm<<<ggrid, gblk, 0, stream>>>(agg, W2, xp, N, HC, D_IN);
  hipMemsetAsync(agg, 0, NF * sizeof(float), stream);   // safe: stream-ordered after GEMM
  k_att<<<(N * NH2 + 255) / 256, 256, 0, stream>>>(xp, as2, ad2, asr2, adt2, N, NH2, NC2);
  k_edge_score<<<(Etot * NH2 + 255) / 256, 256, 0, stream>>>(ei, E, Etot, asr2, adt2, esc2, m2, NH2);
  k_edge_exp<<<(Etot * NH2 + 255) / 256, 256, 0, stream>>>(ei, E, Etot, m2, esc2, den2, NH2);
  k_alpha<<<(Etot * NH2 + 255) / 256, 256, 0, stream>>>(ei, E, Etot, den2, esc2, NH2);
  {
    long long total = (long long)Etot * HC;
    k_agg<<<(int)((total + 255) / 256), 256, 0, stream>>>(ei, E, Etot, esc2, xp, agg, NH2, NC2);
  }

  // ---- epilogue: mean+bias, loss ----
  k_mean<<<(N * NC2 + 255) / 256, 256, 0, stream>>>(agg, b2, out + 1, N);
  k_loss<<<(N * 64 + 255) / 256, 256, 0, stream>>>(out + 1, y, msk, acc, N);
  k_final<<<1, 64, 0, stream>>>(acc, out);
}

// Round 2
// 834.224 us; speedup vs baseline: 1.5505x; 1.5505x over previous
//
#include <hip/hip_runtime.h>
#include <cmath>

#define D_IN 512
#define HC   512   // H1*C1 == H2*C2 == D_IN
#define NH1  8
#define NC1  64
#define NH2  4
#define NC2  128

// ---------------- GEMM: C[M,N] = A[M,K] @ B[K,N], row-major, fp32 ----------
__global__ void k_gemm(const float* __restrict__ A, const float* __restrict__ B,
                       float* __restrict__ C, int M, int N, int K) {
  __shared__ float As[16][65];   // [k][m], padded
  __shared__ float Bs[16][64];   // [k][n]
  int tx = threadIdx.x, ty = threadIdx.y;
  int tid = ty * 16 + tx;
  int m0 = blockIdx.y * 64;
  int n0 = blockIdx.x * 64;
  float acc[4][4] = {};
  for (int k0 = 0; k0 < K; k0 += 16) {
#pragma unroll
    for (int l = 0; l < 4; ++l) {
      int idx = tid + l * 256;
      int mm = idx >> 4, kk = idx & 15;
      int gm = m0 + mm;
      As[kk][mm] = (gm < M) ? A[(size_t)gm * K + k0 + kk] : 0.0f;
    }
#pragma unroll
    for (int l = 0; l < 4; ++l) {
      int idx = tid + l * 256;
      int kk = idx >> 6, nn = idx & 63;
      Bs[kk][nn] = B[(size_t)(k0 + kk) * N + n0 + nn];
    }
    __syncthreads();
#pragma unroll
    for (int k = 0; k < 16; ++k) {
      float a[4], b[4];
#pragma unroll
      for (int i = 0; i < 4; ++i) a[i] = As[k][ty * 4 + i];
#pragma unroll
      for (int j = 0; j < 4; ++j) b[j] = Bs[k][tx * 4 + j];
#pragma unroll
      for (int i = 0; i < 4; ++i)
#pragma unroll
        for (int j = 0; j < 4; ++j) acc[i][j] += a[i] * b[j];
    }
    __syncthreads();
  }
  for (int i = 0; i < 4; ++i) {
    int gm = m0 + ty * 4 + i;
    if (gm >= M) continue;
    for (int j = 0; j < 4; ++j)
      C[(size_t)gm * N + n0 + tx * 4 + j] = acc[i][j];
  }
}

// ------------- attention scores: asrc[n,h] = <xp[n,h,:], att_src[h,:]> -----
__global__ void k_att(const float* __restrict__ xp, const float* __restrict__ att_src,
                      const float* __restrict__ att_dst, float* __restrict__ asrc,
                      float* __restrict__ adst, int N, int H, int C) {
  int idx = blockIdx.x * blockDim.x + threadIdx.x;
  if (idx >= N * H) return;
  int n = idx / H, h = idx - n * H;
  const float* xr = xp + (size_t)n * H * C + (size_t)h * C;
  const float* s = att_src + (size_t)h * C;
  const float* d = att_dst + (size_t)h * C;
  float vs = 0.f, vd = 0.f;
  for (int c = 0; c < C; ++c) { float v = xr[c]; vs += v * s[c]; vd += v * d[c]; }
  asrc[idx] = vs; adst[idx] = vd;
}

__global__ void k_fill(float* __restrict__ p, float v, int n) {
  int i = blockIdx.x * blockDim.x + threadIdx.x;
  if (i < n) p[i] = v;
}

__device__ inline void atomicMaxF(float* addr, float v) {
  unsigned int u = __float_as_uint(v);
  if (u <= 0x7FFFFFFFu) atomicMax((int*)addr, __float_as_int(v));     // v >= +0.0
  else                  atomicMin((unsigned int*)addr, u);            // v < 0 (incl -0.0)
}

// -------- edge score (leaky relu) + segment max over dst --------------------
__global__ void k_edge_score(const int* __restrict__ ei, int E, int Etot,
                             const float* __restrict__ asrc, const float* __restrict__ adst,
                             float* __restrict__ esc, float* __restrict__ m, int H) {
  int idx = blockIdx.x * blockDim.x + threadIdx.x;
  if (idx >= Etot * H) return;
  int e = idx / H, h = idx - e * H;
  int s = (e < E) ? ei[e] : e - E;
  int d = (e < E) ? ei[E + e] : e - E;
  float v = asrc[s * H + h] + adst[d * H + h];
  v = (v > 0.f) ? v : 0.2f * v;
  esc[idx] = v;
  atomicMaxF(&m[d * H + h], v);
}

// -------- exp(e - m[dst]) + segment sum ------------------------------------
__global__ void k_edge_exp(const int* __restrict__ ei, int E, int Etot,
                           const float* __restrict__ m, float* __restrict__ esc,
                           float* __restrict__ den, int H) {
  int idx = blockIdx.x * blockDim.x + threadIdx.x;
  if (idx >= Etot * H) return;
  int e = idx / H, h = idx - e * H;
  int d = (e < E) ? ei[E + e] : e - E;
  float ex = expf(esc[idx] - m[d * H + h]);
  esc[idx] = ex;
  atomicAdd(&den[d * H + h], ex);
}

// ---------------- CSR build ------------------------------------------------
__global__ void k_hist(const int* __restrict__ ei, int E, int Etot, int* __restrict__ cnt) {
  int e = blockIdx.x * blockDim.x + threadIdx.x;
  if (e >= Etot) return;
  int d = (e < E) ? ei[E + e] : e - E;
  atomicAdd(&cnt[d], 1);
}

// single-block exclusive scan over N counts -> rowstart[0..N]
__global__ void k_scan(const int* __restrict__ cnt, int* __restrict__ rowstart, int N) {
  __shared__ int buf[1024];
  __shared__ int carry;
  int tid = threadIdx.x;
  if (tid == 0) carry = 0;
  __syncthreads();
  for (int base = 0; base < N; base += 1024) {
    int i = base + tid;
    int v = (i < N) ? cnt[i] : 0;
    buf[tid] = v;
    __syncthreads();
#pragma unroll
    for (int off = 1; off < 1024; off <<= 1) {
      int t = (tid >= off) ? buf[tid - off] : 0;
      __syncthreads();
      buf[tid] += t;
      __syncthreads();
    }
    if (i < N) rowstart[i] = carry + buf[tid] - v;   // exclusive
    int total = buf[1023];
    __syncthreads();
    if (tid == 0) carry += total;
    __syncthreads();
  }
  if (tid == 0) rowstart[N] = carry;
}

__global__ void k_scatter(const int* __restrict__ ei, int E, int Etot,
                          const int* __restrict__ rowstart, int* __restrict__ cursor,
                          int* __restrict__ csr_src, int* __restrict__ csr_eid) {
  int e = blockIdx.x * blockDim.x + threadIdx.x;
  if (e >= Etot) return;
  int s = (e < E) ? ei[e] : e - E;
  int d = (e < E) ? ei[E + e] : e - E;
  int pos = atomicAdd(&cursor[d], 1);
  int slot = rowstart[d] + pos;
  csr_src[slot] = s;
  csr_eid[slot] = e;
}

// -------- gather aggregation: out[n,hc] = (sum_e esc*xp[src]) / den --------
__global__ void k_agg_csr(const int* __restrict__ rowstart, const int* __restrict__ csr_src,
                          const int* __restrict__ csr_eid, const float* __restrict__ esc,
                          const float* __restrict__ den, const float* __restrict__ xp,
                          float* __restrict__ outb, int H, int C) {
  int n = blockIdx.x;
  int hc = threadIdx.x;          // 512 threads
  int h = hc / C;
  int beg = rowstart[n], end = rowstart[n + 1];
  float acc = 0.f;
  for (int i = beg; i < end; ++i) {
    int s = csr_src[i];
    int e = csr_eid[i];
    acc += esc[e * H + h] * xp[(size_t)s * HC + hc];
  }
  outb[(size_t)n * HC + hc] = acc / (den[n * H + h] + 1e-16f);
}

// -------- h = elu(x + b) in place ------------------------------------------
__global__ void k_elu(float* __restrict__ buf, const float* __restrict__ b, int total) {
  int idx = blockIdx.x * blockDim.x + threadIdx.x;
  if (idx >= total) return;
  float v = buf[idx] + b[idx & (HC - 1)];
  buf[idx] = (v > 0.f) ? v : expm1f(v);
}

// -------- mean over heads + bias -> d_out+1 --------------------------------
__global__ void k_mean(const float* __restrict__ agg, const float* __restrict__ b2,
                       float* __restrict__ out, int N) {
  int idx = blockIdx.x * blockDim.x + threadIdx.x;
  if (idx >= N * NC2) return;
  int n = idx / NC2, c = idx - n * NC2;
  float s = 0.f;
#pragma unroll
  for (int h = 0; h < NH2; ++h) s += agg[(size_t)n * HC + h * NC2 + c];
  out[idx] = s * (1.0f / NH2) + b2[c];
}

// -------- CE loss: one wave per node, atomics spread over 128 slot pairs ---
__global__ void k_loss(const float* __restrict__ out, const int* __restrict__ y,
                       const int* __restrict__ msk, float* __restrict__ acc2, int N) {
  int gtid = blockIdx.x * blockDim.x + threadIdx.x;
  int wave = gtid >> 6;
  int lane = gtid & 63;
  if (wave >= N) return;
  const float* row = out + (size_t)wave * NC2;
  float v0 = row[lane], v1 = row[lane + 64];
  float mx = fmaxf(v0, v1);
#pragma unroll
  for (int o = 32; o > 0; o >>= 1) mx = fmaxf(mx, __shfl_xor(mx, o));
  float se = expf(v0 - mx) + expf(v1 - mx);
#pragma unroll
  for (int o = 32; o > 0; o >>= 1) se += __shfl_xor(se, o);
  if (lane == 0 && msk[wave] != 0) {
    float lse = mx + logf(se);
    float ce = lse - row[y[wave]];
    int slot = blockIdx.x & 127;
    atomicAdd(&acc2[slot], ce);
    atomicAdd(&acc2[128 + slot], 1.0f);
  }
}

__global__ void k_final(const float* __restrict__ acc2, float* __restrict__ out0) {
  int tid = threadIdx.x;   // 128 threads
  float ce = acc2[tid], ct = acc2[128 + tid];
#pragma unroll
  for (int o = 32; o > 0; o >>= 1) { ce += __shfl_xor(ce, o); ct += __shfl_xor(ct, o); }
  __shared__ float s[4];
  if ((tid & 63) == 0) { s[(tid >> 6) * 2] = ce; s[(tid >> 6) * 2 + 1] = ct; }
  __syncthreads();
  if (tid == 0) out0[0] = (s[0] + s[2]) / (s[1] + s[3]);
}

extern "C" void kernel_launch(void* const* d_in, const int* in_sizes, int n_in,
                              void* d_out, int out_size, void* d_ws, size_t ws_size,
                              hipStream_t stream) {
  const float* x   = (const float*)d_in[0];
  const int*   ei  = (const int*)d_in[1];
  const int*   y   = (const int*)d_in[2];
  const int*   msk = (const int*)d_in[3];
  const float* W1  = (const float*)d_in[4];
  const float* as1 = (const float*)d_in[5];
  const float* ad1 = (const float*)d_in[6];
  const float* b1  = (const float*)d_in[7];
  const float* W2  = (const float*)d_in[8];
  const float* as2 = (const float*)d_in[9];
  const float* ad2 = (const float*)d_in[10];
  const float* b2  = (const float*)d_in[11];
  float* out = (float*)d_out;

  int N = in_sizes[0] / D_IN;   // 20000
  int E = in_sizes[1] / 2;      // 100000
  int Etot = E + N;             // 120000 (self-loops appended)

  float* ws = (float*)d_ws;
  size_t NF = (size_t)N * HC;
  float* xp   = ws;                       // N*512
  float* agg  = xp + NF;                  // N*512
  float* asr1 = agg + NF;                 // N*8
  float* adt1 = asr1 + (size_t)N * NH1;   // N*8
  float* asr2 = adt1 + (size_t)N * NH1;   // N*4
  float* adt2 = asr2 + (size_t)N * NH2;   // N*4
  float* m1   = adt2 + (size_t)N * NH2;   // N*8  (-inf fill)
  float* m2   = m1 + (size_t)N * NH1;     // N*4  (-inf fill)
  // ---- zero-init region: den1, den2, acc2, cnt, cursor (contiguous) ----
  float* den1 = m2 + (size_t)N * NH2;     // N*8
  float* den2 = den1 + (size_t)N * NH1;   // N*4
  float* acc2 = den2 + (size_t)N * NH2;   // 256
  int*   cnt    = (int*)(acc2 + 256);     // N
  int*   cursor = cnt + N;                // N
  size_t zero_bytes = ((size_t)N * (NH1 + NH2) + 256 + 2 * (size_t)N) * sizeof(float);
  // ---- fully-written region ----
  int*   rowstart = cursor + N;           // N+1
  int*   csr_src  = rowstart + N + 1;     // Etot
  int*   csr_eid  = csr_src + Etot;       // Etot
  float* esc1 = (float*)(csr_eid + Etot); // Etot*8
  float* esc2 = esc1 + (size_t)Etot * NH1;// Etot*4

  dim3 gblk(16, 16);
  dim3 ggrid(HC / 64, (N + 63) / 64);

  // init
  {
    int nfill = N * (NH1 + NH2);
    k_fill<<<(nfill + 255) / 256, 256, 0, stream>>>(m1, -INFINITY, nfill);
    hipMemsetAsync(den1, 0, zero_bytes, stream);
  }

  // CSR build (shared by both layers)
  k_hist<<<(Etot + 255) / 256, 256, 0, stream>>>(ei, E, Etot, cnt);
  k_scan<<<1, 1024, 0, stream>>>(cnt, rowstart, N);
  k_scatter<<<(Etot + 255) / 256, 256, 0, stream>>>(ei, E, Etot, rowstart, cursor, csr_src, csr_eid);

  // ---- layer 1 ----
  k_gemm<<<ggrid, gblk, 0, stream>>>(x, W1, xp, N, HC, D_IN);
  k_att<<<(N * NH1 + 255) / 256, 256, 0, stream>>>(xp, as1, ad1, asr1, adt1, N, NH1, NC1);
  k_edge_score<<<(Etot * NH1 + 255) / 256, 256, 0, stream>>>(ei, E, Etot, asr1, adt1, esc1, m1, NH1);
  k_edge_exp<<<(Etot * NH1 + 255) / 256, 256, 0, stream>>>(ei, E, Etot, m1, esc1, den1, NH1);
  k_agg_csr<<<N, HC, 0, stream>>>(rowstart, csr_src, csr_eid, esc1, den1, xp, agg, NH1, NC1);
  k_elu<<<(int)((NF + 255) / 256), 256, 0, stream>>>(agg, b1, (int)NF);

  // ---- layer 2 ----
  k_gemm<<<ggrid, gblk, 0, stream>>>(agg, W2, xp, N, HC, D_IN);
  k_att<<<(N * NH2 + 255) / 256, 256, 0, stream>>>(xp, as2, ad2, asr2, adt2, N, NH2, NC2);
  k_edge_score<<<(Etot * NH2 + 255) / 256, 256, 0, stream>>>(ei, E, Etot, asr2, adt2, esc2, m2, NH2);
  k_edge_exp<<<(Etot * NH2 + 255) / 256, 256, 0, stream>>>(ei, E, Etot, m2, esc2, den2, NH2);
  k_agg_csr<<<N, HC, 0, stream>>>(rowstart, csr_src, csr_eid, esc2, den2, xp, agg, NH2, NC2);

  // ---- epilogue: mean+bias, loss ----
  k_mean<<<(N * NC2 + 255) / 256, 256, 0, stream>>>(agg, b2, out + 1, N);
  k_loss<<<(N * 64 + 255) / 256, 256, 0, stream>>>(out + 1, y, msk, acc2, N);
  k_final<<<1, 128, 0, stream>>>(acc2, out);
}

// Round 3
// 583.386 us; speedup vs baseline: 2.2172x; 1.4300x over previous
//
#include <hip/hip_runtime.h>
#include <cmath>

#define D_IN 512
#define HC   512   // H1*C1 == H2*C2 == D_IN
#define NH1  8
#define NC1  64
#define NH2  4
#define NC2  128
#define BM 128
#define BN 128
#define BK 32

typedef __attribute__((ext_vector_type(8))) short short8;
typedef __attribute__((ext_vector_type(4))) float f32x4;

// ---------- fp32 -> bf16 cast (RNE), 4 elems/thread ------------------------
__global__ void k_cast(const float* __restrict__ in, ushort* __restrict__ outp, int n4) {
  int i = blockIdx.x * blockDim.x + threadIdx.x;
  if (i >= n4) return;
  float4 v = ((const float4*)in)[i];
  ushort4 r;
  unsigned u;
  u = __float_as_uint(v.x); r.x = (ushort)((u + 0x7FFFu + ((u >> 16) & 1u)) >> 16);
  u = __float_as_uint(v.y); r.y = (ushort)((u + 0x7FFFu + ((u >> 16) & 1u)) >> 16);
  u = __float_as_uint(v.z); r.z = (ushort)((u + 0x7FFFu + ((u >> 16) & 1u)) >> 16);
  u = __float_as_uint(v.w); r.w = (ushort)((u + 0x7FFFu + ((u >> 16) & 1u)) >> 16);
  ((ushort4*)outp)[i] = r;
}

// ---------- W[K,N] fp32 -> Wt[N,K] bf16 ------------------------------------
__global__ void k_castT(const float* __restrict__ W, ushort* __restrict__ Wt, int K, int N) {
  int idx = blockIdx.x * blockDim.x + threadIdx.x;
  if (idx >= K * N) return;
  int n = idx / K, k = idx - n * K;
  unsigned u = __float_as_uint(W[(size_t)k * N + n]);
  Wt[idx] = (ushort)((u + 0x7FFFu + ((u >> 16) & 1u)) >> 16);
}

// ---------- bf16 MFMA GEMM: C[M,512] = A[M,512] @ Bt[512,512]^T ------------
__global__ void k_gemm_bf16(const ushort* __restrict__ A, const ushort* __restrict__ Bt,
                            float* __restrict__ C, int M) {
  __shared__ __align__(16) ushort As[BM * BK];   // [m][k], row = 32 elems (64B)
  __shared__ __align__(16) ushort Bs[BN * BK];   // [n][k]
  int t = threadIdx.x;
  int m0 = blockIdx.y * BM;
  int n0 = blockIdx.x * BN;
  int wave = t >> 6;
  int lane = t & 63;
  int ln = lane & 15, qd = lane >> 4;
  int wm = (wave >> 1) * 64, wn = (wave & 1) * 64;

  f32x4 acc[4][4] = {};

  // staging map: thread t covers row r = t>>2 (and r+64), k-quad = t&3
  int r  = t >> 2;
  int kq = t & 3;
  int ra0 = m0 + r;      if (ra0 > M - 1) ra0 = M - 1;
  int ra1 = m0 + r + 64; if (ra1 > M - 1) ra1 = M - 1;
  const ushort* gA0 = A + (size_t)ra0 * D_IN + kq * 8;
  const ushort* gA1 = A + (size_t)ra1 * D_IN + kq * 8;
  const ushort* gB0 = Bt + (size_t)(n0 + r) * D_IN + kq * 8;
  const ushort* gB1 = Bt + (size_t)(n0 + r + 64) * D_IN + kq * 8;
  ushort* lA = As + t * 8;       // byte offset t*16
  ushort* lB = Bs + t * 8;

  for (int k0 = 0; k0 < D_IN; k0 += BK) {
    __syncthreads();
    __builtin_amdgcn_global_load_lds((const __attribute__((address_space(1))) void*)(gA0 + k0),
                                     (__attribute__((address_space(3))) void*)lA, 16, 0, 0);
    __builtin_amdgcn_global_load_lds((const __attribute__((address_space(1))) void*)(gA1 + k0),
                                     (__attribute__((address_space(3))) void*)(lA + 64 * BK), 16, 0, 0);
    __builtin_amdgcn_global_load_lds((const __attribute__((address_space(1))) void*)(gB0 + k0),
                                     (__attribute__((address_space(3))) void*)lB, 16, 0, 0);
    __builtin_amdgcn_global_load_lds((const __attribute__((address_space(1))) void*)(gB1 + k0),
                                     (__attribute__((address_space(3))) void*)(lB + 64 * BK), 16, 0, 0);
    __syncthreads();
    short8 a[4], b[4];
#pragma unroll
    for (int i = 0; i < 4; ++i)
      a[i] = *(const short8*)&As[(wm + i * 16 + ln) * BK + qd * 8];
#pragma unroll
    for (int j = 0; j < 4; ++j)
      b[j] = *(const short8*)&Bs[(wn + j * 16 + ln) * BK + qd * 8];
#pragma unroll
    for (int i = 0; i < 4; ++i)
#pragma unroll
      for (int j = 0; j < 4; ++j)
        acc[i][j] = __builtin_amdgcn_mfma_f32_16x16x32_bf16(a[i], b[j], acc[i][j], 0, 0, 0);
  }
  // C/D layout: col = lane&15, row = qd*4 + reg
#pragma unroll
  for (int i = 0; i < 4; ++i) {
#pragma unroll
    for (int reg = 0; reg < 4; ++reg) {
      int row = m0 + wm + i * 16 + qd * 4 + reg;
      if (row >= M) continue;
#pragma unroll
      for (int j = 0; j < 4; ++j)
        C[(size_t)row * HC + n0 + wn + j * 16 + ln] = acc[i][j][reg];
    }
  }
}

// ------------- attention scores: asrc[n,h] = <xp[n,h,:], att_src[h,:]> -----
__global__ void k_att(const float* __restrict__ xp, const float* __restrict__ att_src,
                      const float* __restrict__ att_dst, float* __restrict__ asrc,
                      float* __restrict__ adst, int N, int H, int C) {
  int idx = blockIdx.x * blockDim.x + threadIdx.x;
  if (idx >= N * H) return;
  int n = idx / H, h = idx - n * H;
  const float* xr = xp + (size_t)n * H * C + (size_t)h * C;
  const float* s = att_src + (size_t)h * C;
  const float* d = att_dst + (size_t)h * C;
  float vs = 0.f, vd = 0.f;
  for (int c = 0; c < C; ++c) { float v = xr[c]; vs += v * s[c]; vd += v * d[c]; }
  asrc[idx] = vs; adst[idx] = vd;
}

__global__ void k_fill(float* __restrict__ p, float v, int n) {
  int i = blockIdx.x * blockDim.x + threadIdx.x;
  if (i < n) p[i] = v;
}

__device__ inline void atomicMaxF(float* addr, float v) {
  unsigned int u = __float_as_uint(v);
  if (u <= 0x7FFFFFFFu) atomicMax((int*)addr, __float_as_int(v));     // v >= +0.0
  else                  atomicMin((unsigned int*)addr, u);            // v < 0 (incl -0.0)
}

// -------- edge score (leaky relu) + segment max over dst --------------------
__global__ void k_edge_score(const int* __restrict__ ei, int E, int Etot,
                             const float* __restrict__ asrc, const float* __restrict__ adst,
                             float* __restrict__ esc, float* __restrict__ m, int H) {
  int idx = blockIdx.x * blockDim.x + threadIdx.x;
  if (idx >= Etot * H) return;
  int e = idx / H, h = idx - e * H;
  int s = (e < E) ? ei[e] : e - E;
  int d = (e < E) ? ei[E + e] : e - E;
  float v = asrc[s * H + h] + adst[d * H + h];
  v = (v > 0.f) ? v : 0.2f * v;
  esc[idx] = v;
  atomicMaxF(&m[d * H + h], v);
}

// -------- exp(e - m[dst]) + segment sum ------------------------------------
__global__ void k_edge_exp(const int* __restrict__ ei, int E, int Etot,
                           const float* __restrict__ m, float* __restrict__ esc,
                           float* __restrict__ den, int H) {
  int idx = blockIdx.x * blockDim.x + threadIdx.x;
  if (idx >= Etot * H) return;
  int e = idx / H, h = idx - e * H;
  int d = (e < E) ? ei[E + e] : e - E;
  float ex = expf(esc[idx] - m[d * H + h]);
  esc[idx] = ex;
  atomicAdd(&den[d * H + h], ex);
}

// ---------------- CSR build ------------------------------------------------
__global__ void k_hist(const int* __restrict__ ei, int E, int Etot, int* __restrict__ cnt) {
  int e = blockIdx.x * blockDim.x + threadIdx.x;
  if (e >= Etot) return;
  int d = (e < E) ? ei[E + e] : e - E;
  atomicAdd(&cnt[d], 1);
}

// single-block exclusive scan over N counts -> rowstart[0..N]
__global__ void k_scan(const int* __restrict__ cnt, int* __restrict__ rowstart, int N) {
  __shared__ int buf[1024];
  __shared__ int carry;
  int tid = threadIdx.x;
  if (tid == 0) carry = 0;
  __syncthreads();
  for (int base = 0; base < N; base += 1024) {
    int i = base + tid;
    int v = (i < N) ? cnt[i] : 0;
    buf[tid] = v;
    __syncthreads();
#pragma unroll
    for (int off = 1; off < 1024; off <<= 1) {
      int t = (tid >= off) ? buf[tid - off] : 0;
      __syncthreads();
      buf[tid] += t;
      __syncthreads();
    }
    if (i < N) rowstart[i] = carry + buf[tid] - v;   // exclusive
    int total = buf[1023];
    __syncthreads();
    if (tid == 0) carry += total;
    __syncthreads();
  }
  if (tid == 0) rowstart[N] = carry;
}

__global__ void k_scatter(const int* __restrict__ ei, int E, int Etot,
                          const int* __restrict__ rowstart, int* __restrict__ cursor,
                          int* __restrict__ csr_src, int* __restrict__ csr_eid) {
  int e = blockIdx.x * blockDim.x + threadIdx.x;
  if (e >= Etot) return;
  int s = (e < E) ? ei[e] : e - E;
  int d = (e < E) ? ei[E + e] : e - E;
  int pos = atomicAdd(&cursor[d], 1);
  int slot = rowstart[d] + pos;
  csr_src[slot] = s;
  csr_eid[slot] = e;
}

// -------- gather aggregation: out[n,hc] = (sum_e esc*xp[src]) / den --------
__global__ void k_agg_csr(const int* __restrict__ rowstart, const int* __restrict__ csr_src,
                          const int* __restrict__ csr_eid, const float* __restrict__ esc,
                          const float* __restrict__ den, const float* __restrict__ xp,
                          float* __restrict__ outb, int H, int C) {
  int n = blockIdx.x;
  int hc = threadIdx.x;          // 512 threads
  int h = hc / C;
  int beg = rowstart[n], end = rowstart[n + 1];
  float acc = 0.f;
  for (int i = beg; i < end; ++i) {
    int s = csr_src[i];
    int e = csr_eid[i];
    acc += esc[e * H + h] * xp[(size_t)s * HC + hc];
  }
  outb[(size_t)n * HC + hc] = acc / (den[n * H + h] + 1e-16f);
}

// -------- h = elu(x + b) in place ------------------------------------------
__global__ void k_elu(float* __restrict__ buf, const float* __restrict__ b, int total) {
  int idx = blockIdx.x * blockDim.x + threadIdx.x;
  if (idx >= total) return;
  float v = buf[idx] + b[idx & (HC - 1)];
  buf[idx] = (v > 0.f) ? v : expm1f(v);
}

// -------- mean over heads + bias -> d_out+1 --------------------------------
__global__ void k_mean(const float* __restrict__ agg, const float* __restrict__ b2,
                       float* __restrict__ out, int N) {
  int idx = blockIdx.x * blockDim.x + threadIdx.x;
  if (idx >= N * NC2) return;
  int n = idx / NC2, c = idx - n * NC2;
  float s = 0.f;
#pragma unroll
  for (int h = 0; h < NH2; ++h) s += agg[(size_t)n * HC + h * NC2 + c];
  out[idx] = s * (1.0f / NH2) + b2[c];
}

// -------- CE loss: one wave per node, atomics spread over 128 slot pairs ---
__global__ void k_loss(const float* __restrict__ out, const int* __restrict__ y,
                       const int* __restrict__ msk, float* __restrict__ acc2, int N) {
  int gtid = blockIdx.x * blockDim.x + threadIdx.x;
  int wave = gtid >> 6;
  int lane = gtid & 63;
  if (wave >= N) return;
  const float* row = out + (size_t)wave * NC2;
  float v0 = row[lane], v1 = row[lane + 64];
  float mx = fmaxf(v0, v1);
#pragma unroll
  for (int o = 32; o > 0; o >>= 1) mx = fmaxf(mx, __shfl_xor(mx, o));
  float se = expf(v0 - mx) + expf(v1 - mx);
#pragma unroll
  for (int o = 32; o > 0; o >>= 1) se += __shfl_xor(se, o);
  if (lane == 0 && msk[wave] != 0) {
    float lse = mx + logf(se);
    float ce = lse - row[y[wave]];
    int slot = blockIdx.x & 127;
    atomicAdd(&acc2[slot], ce);
    atomicAdd(&acc2[128 + slot], 1.0f);
  }
}

__global__ void k_final(const float* __restrict__ acc2, float* __restrict__ out0) {
  int tid = threadIdx.x;   // 128 threads
  float ce = acc2[tid], ct = acc2[128 + tid];
#pragma unroll
  for (int o = 32; o > 0; o >>= 1) { ce += __shfl_xor(ce, o); ct += __shfl_xor(ct, o); }
  __shared__ float s[4];
  if ((tid & 63) == 0) { s[(tid >> 6) * 2] = ce; s[(tid >> 6) * 2 + 1] = ct; }
  __syncthreads();
  if (tid == 0) out0[0] = (s[0] + s[2]) / (s[1] + s[3]);
}

extern "C" void kernel_launch(void* const* d_in, const int* in_sizes, int n_in,
                              void* d_out, int out_size, void* d_ws, size_t ws_size,
                              hipStream_t stream) {
  const float* x   = (const float*)d_in[0];
  const int*   ei  = (const int*)d_in[1];
  const int*   y   = (const int*)d_in[2];
  const int*   msk = (const int*)d_in[3];
  const float* W1  = (const float*)d_in[4];
  const float* as1 = (const float*)d_in[5];
  const float* ad1 = (const float*)d_in[6];
  const float* b1  = (const float*)d_in[7];
  const float* W2  = (const float*)d_in[8];
  const float* as2 = (const float*)d_in[9];
  const float* ad2 = (const float*)d_in[10];
  const float* b2  = (const float*)d_in[11];
  float* out = (float*)d_out;

  int N = in_sizes[0] / D_IN;   // 20000
  int E = in_sizes[1] / 2;      // 100000
  int Etot = E + N;             // 120000 (self-loops appended)

  float* ws = (float*)d_ws;
  size_t NF = (size_t)N * HC;
  float* xp   = ws;                       // N*512
  float* agg  = xp + NF;                  // N*512
  float* asr1 = agg + NF;                 // N*8
  float* adt1 = asr1 + (size_t)N * NH1;   // N*8
  float* asr2 = adt1 + (size_t)N * NH1;   // N*4
  float* adt2 = asr2 + (size_t)N * NH2;   // N*4
  float* m1   = adt2 + (size_t)N * NH2;   // N*8  (-inf fill)
  float* m2   = m1 + (size_t)N * NH1;     // N*4  (-inf fill)
  // ---- zero-init region: den1, den2, acc2, cnt, cursor (contiguous) ----
  float* den1 = m2 + (size_t)N * NH2;     // N*8
  float* den2 = den1 + (size_t)N * NH1;   // N*4
  float* acc2 = den2 + (size_t)N * NH2;   // 256
  int*   cnt    = (int*)(acc2 + 256);     // N
  int*   cursor = cnt + N;                // N
  size_t zero_bytes = ((size_t)N * (NH1 + NH2) + 256 + 2 * (size_t)N) * sizeof(float);
  // ---- fully-written region ----
  int*   rowstart = cursor + N;           // N+1
  int*   csr_src  = rowstart + N + 1;     // Etot
  int*   csr_eid  = csr_src + Etot;       // Etot
  float* esc1 = (float*)(csr_eid + Etot); // Etot*8
  float* esc2 = esc1 + (size_t)Etot * NH1;// Etot*4
  ushort* Abf = (ushort*)((((uintptr_t)(esc2 + (size_t)Etot * NH2)) + 15) & ~(uintptr_t)15);
  ushort* Wt1 = Abf + NF;                 // 512*512
  ushort* Wt2 = Wt1 + (size_t)D_IN * HC;  // 512*512

  // init
  {
    int nfill = N * (NH1 + NH2);
    k_fill<<<(nfill + 255) / 256, 256, 0, stream>>>(m1, -INFINITY, nfill);
    hipMemsetAsync(den1, 0, zero_bytes, stream);
  }

  // weight transpose-casts (both layers)
  k_castT<<<(D_IN * HC + 255) / 256, 256, 0, stream>>>(W1, Wt1, D_IN, HC);
  k_castT<<<(D_IN * HC + 255) / 256, 256, 0, stream>>>(W2, Wt2, D_IN, HC);

  // CSR build (shared by both layers)
  k_hist<<<(Etot + 255) / 256, 256, 0, stream>>>(ei, E, Etot, cnt);
  k_scan<<<1, 1024, 0, stream>>>(cnt, rowstart, N);
  k_scatter<<<(Etot + 255) / 256, 256, 0, stream>>>(ei, E, Etot, rowstart, cursor, csr_src, csr_eid);

  dim3 ggrid(HC / BN, (N + BM - 1) / BM);

  // ---- layer 1 ----
  k_cast<<<(int)((NF / 4 + 255) / 256), 256, 0, stream>>>(x, Abf, (int)(NF / 4));
  k_gemm_bf16<<<ggrid, 256, 0, stream>>>(Abf, Wt1, xp, N);
  k_att<<<(N * NH1 + 255) / 256, 256, 0, stream>>>(xp, as1, ad1, asr1, adt1, N, NH1, NC1);
  k_edge_score<<<(Etot * NH1 + 255) / 256, 256, 0, stream>>>(ei, E, Etot, asr1, adt1, esc1, m1, NH1);
  k_edge_exp<<<(Etot * NH1 + 255) / 256, 256, 0, stream>>>(ei, E, Etot, m1, esc1, den1, NH1);
  k_agg_csr<<<N, HC, 0, stream>>>(rowstart, csr_src, csr_eid, esc1, den1, xp, agg, NH1, NC1);
  k_elu<<<(int)((NF + 255) / 256), 256, 0, stream>>>(agg, b1, (int)NF);

  // ---- layer 2 ----
  k_cast<<<(int)((NF / 4 + 255) / 256), 256, 0, stream>>>(agg, Abf, (int)(NF / 4));
  k_gemm_bf16<<<ggrid, 256, 0, stream>>>(Abf, Wt2, xp, N);
  k_att<<<(N * NH2 + 255) / 256, 256, 0, stream>>>(xp, as2, ad2, asr2, adt2, N, NH2, NC2);
  k_edge_score<<<(Etot * NH2 + 255) / 256, 256, 0, stream>>>(ei, E, Etot, asr2, adt2, esc2, m2, NH2);
  k_edge_exp<<<(Etot * NH2 + 255) / 256, 256, 0, stream>>>(ei, E, Etot, m2, esc2, den2, NH2);
  k_agg_csr<<<N, HC, 0, stream>>>(rowstart, csr_src, csr_eid, esc2, den2, xp, agg, NH2, NC2);

  // ---- epilogue: mean+bias, loss ----
  k_mean<<<(N * NC2 + 255) / 256, 256, 0, stream>>>(agg, b2, out + 1, N);
  k_loss<<<(N * 64 + 255) / 256, 256, 0, stream>>>(out + 1, y, msk, acc2, N);
  k_final<<<1, 128, 0, stream>>>(acc2, out);
}

// Round 4
// 390.973 us; speedup vs baseline: 3.3084x; 1.4921x over previous
//
#include <hip/hip_runtime.h>
#include <cmath>

#define D_IN 512
#define HC   512   // H1*C1 == H2*C2 == D_IN
#define NH1  8
#define NC1  64
#define NH2  4
#define NC2  128
#define BM 128
#define BN 128
#define BK 32

typedef __attribute__((ext_vector_type(8))) short short8;
typedef __attribute__((ext_vector_type(4))) float f32x4;

__device__ inline ushort f2bf(float f) {
  unsigned u = __float_as_uint(f);
  return (ushort)((u + 0x7FFFu + ((u >> 16) & 1u)) >> 16);
}
__device__ inline float bf2f(ushort b) { return __uint_as_float(((unsigned)b) << 16); }

// ---------- fp32 -> bf16 cast (RNE), 4 elems/thread ------------------------
__global__ void k_cast(const float* __restrict__ in, ushort* __restrict__ outp, int n4) {
  int i = blockIdx.x * blockDim.x + threadIdx.x;
  if (i >= n4) return;
  float4 v = ((const float4*)in)[i];
  ushort4 r = { f2bf(v.x), f2bf(v.y), f2bf(v.z), f2bf(v.w) };
  ((ushort4*)outp)[i] = r;
}

// ---------- W[K,N] fp32 -> Wt[N,K] bf16 ------------------------------------
__global__ void k_castT(const float* __restrict__ W, ushort* __restrict__ Wt, int K, int N) {
  int idx = blockIdx.x * blockDim.x + threadIdx.x;
  if (idx >= K * N) return;
  int n = idx / K, k = idx - n * K;
  Wt[idx] = f2bf(W[(size_t)k * N + n]);
}

// ---------- bf16 MFMA GEMM: Cbf[M,512] = A[M,512] @ Bt[512,512]^T ----------
__global__ void k_gemm_bf16(const ushort* __restrict__ A, const ushort* __restrict__ Bt,
                            ushort* __restrict__ Cbf, int M) {
  __shared__ __align__(16) ushort As[BM * BK];   // [m][k]
  __shared__ __align__(16) ushort Bs[BN * BK];   // [n][k]
  int t = threadIdx.x;
  int m0 = blockIdx.y * BM;
  int n0 = blockIdx.x * BN;
  int wave = t >> 6;
  int lane = t & 63;
  int ln = lane & 15, qd = lane >> 4;
  int wm = (wave >> 1) * 64, wn = (wave & 1) * 64;

  f32x4 acc[4][4] = {};

  int r  = t >> 2;
  int kq = t & 3;
  int ra0 = m0 + r;      if (ra0 > M - 1) ra0 = M - 1;
  int ra1 = m0 + r + 64; if (ra1 > M - 1) ra1 = M - 1;
  const ushort* gA0 = A + (size_t)ra0 * D_IN + kq * 8;
  const ushort* gA1 = A + (size_t)ra1 * D_IN + kq * 8;
  const ushort* gB0 = Bt + (size_t)(n0 + r) * D_IN + kq * 8;
  const ushort* gB1 = Bt + (size_t)(n0 + r + 64) * D_IN + kq * 8;
  ushort* lA = As + t * 8;
  ushort* lB = Bs + t * 8;

  for (int k0 = 0; k0 < D_IN; k0 += BK) {
    __syncthreads();
    __builtin_amdgcn_global_load_lds((const __attribute__((address_space(1))) void*)(gA0 + k0),
                                     (__attribute__((address_space(3))) void*)lA, 16, 0, 0);
    __builtin_amdgcn_global_load_lds((const __attribute__((address_space(1))) void*)(gA1 + k0),
                                     (__attribute__((address_space(3))) void*)(lA + 64 * BK), 16, 0, 0);
    __builtin_amdgcn_global_load_lds((const __attribute__((address_space(1))) void*)(gB0 + k0),
                                     (__attribute__((address_space(3))) void*)lB, 16, 0, 0);
    __builtin_amdgcn_global_load_lds((const __attribute__((address_space(1))) void*)(gB1 + k0),
                                     (__attribute__((address_space(3))) void*)(lB + 64 * BK), 16, 0, 0);
    __syncthreads();
    short8 a[4], b[4];
#pragma unroll
    for (int i = 0; i < 4; ++i)
      a[i] = *(const short8*)&As[(wm + i * 16 + ln) * BK + qd * 8];
#pragma unroll
    for (int j = 0; j < 4; ++j)
      b[j] = *(const short8*)&Bs[(wn + j * 16 + ln) * BK + qd * 8];
#pragma unroll
    for (int i = 0; i < 4; ++i)
#pragma unroll
      for (int j = 0; j < 4; ++j)
        acc[i][j] = __builtin_amdgcn_mfma_f32_16x16x32_bf16(a[i], b[j], acc[i][j], 0, 0, 0);
  }
  // C/D layout: col = lane&15, row = qd*4 + reg
#pragma unroll
  for (int i = 0; i < 4; ++i) {
#pragma unroll
    for (int reg = 0; reg < 4; ++reg) {
      int row = m0 + wm + i * 16 + qd * 4 + reg;
      if (row >= M) continue;
#pragma unroll
      for (int j = 0; j < 4; ++j)
        Cbf[(size_t)row * HC + n0 + wn + j * 16 + ln] = f2bf(acc[i][j][reg]);
    }
  }
}

// ------------- attention scores from bf16 xp -------------------------------
__global__ void k_att(const ushort* __restrict__ xp, const float* __restrict__ att_src,
                      const float* __restrict__ att_dst, float* __restrict__ asrc,
                      float* __restrict__ adst, int N, int H, int C) {
  int idx = blockIdx.x * blockDim.x + threadIdx.x;
  if (idx >= N * H) return;
  int n = idx / H, h = idx - n * H;
  const ushort4* xr = (const ushort4*)(xp + (size_t)n * HC + (size_t)h * C);
  const float* s = att_src + (size_t)h * C;
  const float* d = att_dst + (size_t)h * C;
  float vs = 0.f, vd = 0.f;
  for (int c4 = 0; c4 < C / 4; ++c4) {
    ushort4 v = xr[c4];
    float f0 = bf2f(v.x), f1 = bf2f(v.y), f2 = bf2f(v.z), f3 = bf2f(v.w);
    const float* sc = s + c4 * 4;
    const float* dc = d + c4 * 4;
    vs += f0 * sc[0] + f1 * sc[1] + f2 * sc[2] + f3 * sc[3];
    vd += f0 * dc[0] + f1 * dc[1] + f2 * dc[2] + f3 * dc[3];
  }
  asrc[idx] = vs; adst[idx] = vd;
}

__global__ void k_fill(float* __restrict__ p, float v, int n) {
  int i = blockIdx.x * blockDim.x + threadIdx.x;
  if (i < n) p[i] = v;
}

__device__ inline void atomicMaxF(float* addr, float v) {
  unsigned int u = __float_as_uint(v);
  if (u <= 0x7FFFFFFFu) atomicMax((int*)addr, __float_as_int(v));     // v >= +0.0
  else                  atomicMin((unsigned int*)addr, u);            // v < 0 (incl -0.0)
}

// ---------------- CSR build ------------------------------------------------
__global__ void k_hist(const int* __restrict__ ei, int E, int Etot, int* __restrict__ cnt) {
  int e = blockIdx.x * blockDim.x + threadIdx.x;
  if (e >= Etot) return;
  int d = (e < E) ? ei[E + e] : e - E;
  atomicAdd(&cnt[d], 1);
}

__global__ void k_scan(const int* __restrict__ cnt, int* __restrict__ rowstart, int N) {
  __shared__ int buf[1024];
  __shared__ int carry;
  int tid = threadIdx.x;
  if (tid == 0) carry = 0;
  __syncthreads();
  for (int base = 0; base < N; base += 1024) {
    int i = base + tid;
    int v = (i < N) ? cnt[i] : 0;
    buf[tid] = v;
    __syncthreads();
#pragma unroll
    for (int off = 1; off < 1024; off <<= 1) {
      int t = (tid >= off) ? buf[tid - off] : 0;
      __syncthreads();
      buf[tid] += t;
      __syncthreads();
    }
    if (i < N) rowstart[i] = carry + buf[tid] - v;   // exclusive
    int total = buf[1023];
    __syncthreads();
    if (tid == 0) carry += total;
    __syncthreads();
  }
  if (tid == 0) rowstart[N] = carry;
}

__global__ void k_scatter(const int* __restrict__ ei, int E, int Etot,
                          const int* __restrict__ rowstart, int* __restrict__ cursor,
                          int* __restrict__ csr_src, int* __restrict__ csr_dst) {
  int e = blockIdx.x * blockDim.x + threadIdx.x;
  if (e >= Etot) return;
  int s = (e < E) ? ei[e] : e - E;
  int d = (e < E) ? ei[E + e] : e - E;
  int pos = atomicAdd(&cursor[d], 1);
  int slot = rowstart[d] + pos;
  csr_src[slot] = s;
  csr_dst[slot] = d;
}

// -------- edge score (leaky relu) + segment max, CSR slot order ------------
__global__ void k_edge_score(const int* __restrict__ csr_src, const int* __restrict__ csr_dst,
                             int Etot, const float* __restrict__ asrc,
                             const float* __restrict__ adst,
                             float* __restrict__ esc, float* __restrict__ m, int H) {
  int idx = blockIdx.x * blockDim.x + threadIdx.x;
  if (idx >= Etot * H) return;
  int slot = idx / H, h = idx - slot * H;
  int s = csr_src[slot], d = csr_dst[slot];
  float v = asrc[s * H + h] + adst[d * H + h];
  v = (v > 0.f) ? v : 0.2f * v;
  esc[idx] = v;
  atomicMaxF(&m[d * H + h], v);
}

// -------- exp(e - m[dst]) + segment sum, CSR slot order --------------------
__global__ void k_edge_exp(const int* __restrict__ csr_dst, int Etot,
                           const float* __restrict__ m, float* __restrict__ esc,
                           float* __restrict__ den, int H) {
  int idx = blockIdx.x * blockDim.x + threadIdx.x;
  if (idx >= Etot * H) return;
  int slot = idx / H, h = idx - slot * H;
  int d = csr_dst[slot];
  float ex = expf(esc[idx] - m[d * H + h]);
  esc[idx] = ex;
  atomicAdd(&den[d * H + h], ex);
}

// -------- gather aggregation, 128 thr/node, LDS-staged edges ---------------
// mode 1: hout = bf16(elu(sum/den + b))   (layer 1)
// mode 2: out2[n,c] = mean_h(sum/den) + b[c]  (layer 2, fp32)
__global__ void k_agg(const int* __restrict__ rowstart, const int* __restrict__ csr_src,
                      const float* __restrict__ esc, const float* __restrict__ den,
                      const ushort* __restrict__ xp, ushort* __restrict__ hout,
                      float* __restrict__ out2, const float* __restrict__ bias,
                      int H, int mode) {
  int n = blockIdx.x;
  int tid = threadIdx.x;                 // 128
  int C = HC / H;
  int h = (tid * 4) / C;
  int beg = rowstart[n], end = rowstart[n + 1];
  int CHUNK = 128 / H;                   // 16 (H=8) or 32 (H=4)

  __shared__ int   s_src[32];
  __shared__ float s_a[128];
  __shared__ float s_out[512];

  float ax = 0.f, ay = 0.f, az = 0.f, aw = 0.f;

  for (int c0 = beg; c0 < end; c0 += CHUNK) {
    int len = end - c0; if (len > CHUNK) len = CHUNK;
    __syncthreads();
    if (tid < len) s_src[tid] = csr_src[c0 + tid];
    if (tid < len * H) s_a[tid] = esc[c0 * H + tid];
    __syncthreads();
    for (int i = 0; i < len; ++i) {
      int s = s_src[i];
      float w = s_a[i * H + h];
      ushort4 v = ((const ushort4*)xp)[(size_t)s * 128 + tid];
      ax += w * bf2f(v.x); ay += w * bf2f(v.y);
      az += w * bf2f(v.z); aw += w * bf2f(v.w);
    }
  }
  float rdn = 1.0f / (den[n * H + h] + 1e-16f);
  ax *= rdn; ay *= rdn; az *= rdn; aw *= rdn;

  if (mode == 1) {
    int hc = tid * 4;
    float v0 = ax + bias[hc], v1 = ay + bias[hc + 1];
    float v2 = az + bias[hc + 2], v3 = aw + bias[hc + 3];
    v0 = (v0 > 0.f) ? v0 : expm1f(v0);
    v1 = (v1 > 0.f) ? v1 : expm1f(v1);
    v2 = (v2 > 0.f) ? v2 : expm1f(v2);
    v3 = (v3 > 0.f) ? v3 : expm1f(v3);
    ushort4 r = { f2bf(v0), f2bf(v1), f2bf(v2), f2bf(v3) };
    ((ushort4*)hout)[(size_t)n * 128 + tid] = r;
  } else {
    int hc = tid * 4;
    s_out[hc] = ax; s_out[hc + 1] = ay; s_out[hc + 2] = az; s_out[hc + 3] = aw;
    __syncthreads();
    if (tid < 32) {
      for (int k = 0; k < 4; ++k) {
        int c = tid * 4 + k;
        float sum = s_out[c] + s_out[128 + c] + s_out[256 + c] + s_out[384 + c];
        out2[(size_t)n * NC2 + c] = sum * 0.25f + bias[c];
      }
    }
  }
}

// -------- CE loss: one wave per node, atomics spread over 128 slot pairs ---
__global__ void k_loss(const float* __restrict__ out, const int* __restrict__ y,
                       const int* __restrict__ msk, float* __restrict__ acc2, int N) {
  int gtid = blockIdx.x * blockDim.x + threadIdx.x;
  int wave = gtid >> 6;
  int lane = gtid & 63;
  if (wave >= N) return;
  const float* row = out + (size_t)wave * NC2;
  float v0 = row[lane], v1 = row[lane + 64];
  float mx = fmaxf(v0, v1);
#pragma unroll
  for (int o = 32; o > 0; o >>= 1) mx = fmaxf(mx, __shfl_xor(mx, o));
  float se = expf(v0 - mx) + expf(v1 - mx);
#pragma unroll
  for (int o = 32; o > 0; o >>= 1) se += __shfl_xor(se, o);
  if (lane == 0 && msk[wave] != 0) {
    float lse = mx + logf(se);
    float ce = lse - row[y[wave]];
    int slot = blockIdx.x & 127;
    atomicAdd(&acc2[slot], ce);
    atomicAdd(&acc2[128 + slot], 1.0f);
  }
}

__global__ void k_final(const float* __restrict__ acc2, float* __restrict__ out0) {
  int tid = threadIdx.x;   // 128 threads
  float ce = acc2[tid], ct = acc2[128 + tid];
#pragma unroll
  for (int o = 32; o > 0; o >>= 1) { ce += __shfl_xor(ce, o); ct += __shfl_xor(ct, o); }
  __shared__ float s[4];
  if ((tid & 63) == 0) { s[(tid >> 6) * 2] = ce; s[(tid >> 6) * 2 + 1] = ct; }
  __syncthreads();
  if (tid == 0) out0[0] = (s[0] + s[2]) / (s[1] + s[3]);
}

extern "C" void kernel_launch(void* const* d_in, const int* in_sizes, int n_in,
                              void* d_out, int out_size, void* d_ws, size_t ws_size,
                              hipStream_t stream) {
  const float* x   = (const float*)d_in[0];
  const int*   ei  = (const int*)d_in[1];
  const int*   y   = (const int*)d_in[2];
  const int*   msk = (const int*)d_in[3];
  const float* W1  = (const float*)d_in[4];
  const float* as1 = (const float*)d_in[5];
  const float* ad1 = (const float*)d_in[6];
  const float* b1  = (const float*)d_in[7];
  const float* W2  = (const float*)d_in[8];
  const float* as2 = (const float*)d_in[9];
  const float* ad2 = (const float*)d_in[10];
  const float* b2  = (const float*)d_in[11];
  float* out = (float*)d_out;

  int N = in_sizes[0] / D_IN;   // 20000
  int E = in_sizes[1] / 2;      // 100000
  int Etot = E + N;             // 120000 (self-loops appended)

  float* ws = (float*)d_ws;
  size_t NF = (size_t)N * HC;
  float* asr1 = ws;                       // N*8
  float* adt1 = asr1 + (size_t)N * NH1;   // N*8
  float* asr2 = adt1 + (size_t)N * NH1;   // N*4
  float* adt2 = asr2 + (size_t)N * NH2;   // N*4
  float* m1   = adt2 + (size_t)N * NH2;   // N*8  (-inf fill)
  float* m2   = m1 + (size_t)N * NH1;     // N*4  (-inf fill)
  // ---- zero-init region: den1, den2, acc2, cnt, cursor (contiguous) ----
  float* den1 = m2 + (size_t)N * NH2;     // N*8
  float* den2 = den1 + (size_t)N * NH1;   // N*4
  float* acc2 = den2 + (size_t)N * NH2;   // 256
  int*   cnt    = (int*)(acc2 + 256);     // N
  int*   cursor = cnt + N;                // N
  size_t zero_bytes = ((size_t)N * (NH1 + NH2) + 256 + 2 * (size_t)N) * sizeof(float);
  // ---- fully-written region ----
  int*   rowstart = cursor + N;           // N+1
  int*   csr_src  = rowstart + N + 1;     // Etot
  int*   csr_dst  = csr_src + Etot;       // Etot
  float* esc1 = (float*)(csr_dst + Etot); // Etot*8
  float* esc2 = esc1 + (size_t)Etot * NH1;// Etot*4
  ushort* xpbf = (ushort*)((((uintptr_t)(esc2 + (size_t)Etot * NH2)) + 15) & ~(uintptr_t)15);
  ushort* Abf = xpbf + NF;                // N*512
  ushort* Wt1 = Abf + NF;                 // 512*512
  ushort* Wt2 = Wt1 + (size_t)D_IN * HC;  // 512*512

  // init
  {
    int nfill = N * (NH1 + NH2);
    k_fill<<<(nfill + 255) / 256, 256, 0, stream>>>(m1, -INFINITY, nfill);
    hipMemsetAsync(den1, 0, zero_bytes, stream);
  }

  // weight transpose-casts (both layers)
  k_castT<<<(D_IN * HC + 255) / 256, 256, 0, stream>>>(W1, Wt1, D_IN, HC);
  k_castT<<<(D_IN * HC + 255) / 256, 256, 0, stream>>>(W2, Wt2, D_IN, HC);

  // CSR build (shared by both layers)
  k_hist<<<(Etot + 255) / 256, 256, 0, stream>>>(ei, E, Etot, cnt);
  k_scan<<<1, 1024, 0, stream>>>(cnt, rowstart, N);
  k_scatter<<<(Etot + 255) / 256, 256, 0, stream>>>(ei, E, Etot, rowstart, cursor, csr_src, csr_dst);

  dim3 ggrid(HC / BN, (N + BM - 1) / BM);

  // ---- layer 1 ----
  k_cast<<<(int)((NF / 4 + 255) / 256), 256, 0, stream>>>(x, Abf, (int)(NF / 4));
  k_gemm_bf16<<<ggrid, 256, 0, stream>>>(Abf, Wt1, xpbf, N);
  k_att<<<(N * NH1 + 255) / 256, 256, 0, stream>>>(xpbf, as1, ad1, asr1, adt1, N, NH1, NC1);
  k_edge_score<<<(Etot * NH1 + 255) / 256, 256, 0, stream>>>(csr_src, csr_dst, Etot, asr1, adt1, esc1, m1, NH1);
  k_edge_exp<<<(Etot * NH1 + 255) / 256, 256, 0, stream>>>(csr_dst, Etot, m1, esc1, den1, NH1);
  k_agg<<<N, 128, 0, stream>>>(rowstart, csr_src, esc1, den1, xpbf, Abf, nullptr, b1, NH1, 1);

  // ---- layer 2 ----
  k_gemm_bf16<<<ggrid, 256, 0, stream>>>(Abf, Wt2, xpbf, N);
  k_att<<<(N * NH2 + 255) / 256, 256, 0, stream>>>(xpbf, as2, ad2, asr2, adt2, N, NH2, NC2);
  k_edge_score<<<(Etot * NH2 + 255) / 256, 256, 0, stream>>>(csr_src, csr_dst, Etot, asr2, adt2, esc2, m2, NH2);
  k_edge_exp<<<(Etot * NH2 + 255) / 256, 256, 0, stream>>>(csr_dst, Etot, m2, esc2, den2, NH2);
  k_agg<<<N, 128, 0, stream>>>(rowstart, csr_src, esc2, den2, xpbf, nullptr, out + 1, b2, NH2, 2);

  // ---- epilogue: loss ----
  k_loss<<<(N * 64 + 255) / 256, 256, 0, stream>>>(out + 1, y, msk, acc2, N);
  k_final<<<1, 128, 0, stream>>>(acc2, out);
}

// Round 5
// 335.796 us; speedup vs baseline: 3.8520x; 1.1643x over previous
//
#include <hip/hip_runtime.h>
#include <cmath>

#define D_IN 512
#define HC   512   // H1*C1 == H2*C2 == D_IN
#define NH1  8
#define NC1  64
#define NH2  4
#define NC2  128
#define BM 128
#define BN 128
#define BK 32

typedef __attribute__((ext_vector_type(8))) short short8;
typedef __attribute__((ext_vector_type(4))) float f32x4;

__device__ inline ushort f2bf(float f) {
  unsigned u = __float_as_uint(f);
  return (ushort)((u + 0x7FFFu + ((u >> 16) & 1u)) >> 16);
}
__device__ inline float bf2f(ushort b) { return __uint_as_float(((unsigned)b) << 16); }

// ---------- fp32 -> bf16 cast (RNE), 4 elems/thread ------------------------
__global__ void k_cast(const float* __restrict__ in, ushort* __restrict__ outp, int n4) {
  int i = blockIdx.x * blockDim.x + threadIdx.x;
  if (i >= n4) return;
  float4 v = ((const float4*)in)[i];
  ushort4 r = { f2bf(v.x), f2bf(v.y), f2bf(v.z), f2bf(v.w) };
  ((ushort4*)outp)[i] = r;
}

// ---------- W[K,N] fp32 -> Wt[N,K] bf16 ------------------------------------
__global__ void k_castT(const float* __restrict__ W, ushort* __restrict__ Wt, int K, int N) {
  int idx = blockIdx.x * blockDim.x + threadIdx.x;
  if (idx >= K * N) return;
  int n = idx / K, k = idx - n * K;
  Wt[idx] = f2bf(W[(size_t)k * N + n]);
}

// ---------- bf16 MFMA GEMM + fused attention-score epilogue ----------------
// Cbf[M,512] = A[M,512] @ Bt^T ; asrc[n,h] = <xp[n,h,:], att_s[h,:]> likewise adst.
// C==64: each (row,head) owned by exactly one wave -> plain store.
// C==128: two waves (wn=0/64) share a head -> atomicAdd (needs zeroed asrc/adst).
template<int H>
__global__ void k_gemm_bf16(const ushort* __restrict__ A, const ushort* __restrict__ Bt,
                            ushort* __restrict__ Cbf,
                            const float* __restrict__ att_s, const float* __restrict__ att_d,
                            float* __restrict__ asrc, float* __restrict__ adst, int M) {
  constexpr int C = HC / H;
  __shared__ __align__(16) ushort As[BM * BK];   // [m][k]
  __shared__ __align__(16) ushort Bs[BN * BK];   // [n][k]
  int t = threadIdx.x;
  int m0 = blockIdx.y * BM;
  int n0 = blockIdx.x * BN;
  int wave = t >> 6;
  int lane = t & 63;
  int ln = lane & 15, qd = lane >> 4;
  int wm = (wave >> 1) * 64, wn = (wave & 1) * 64;

  f32x4 acc[4][4] = {};

  int r  = t >> 2;
  int kq = t & 3;
  int ra0 = m0 + r;      if (ra0 > M - 1) ra0 = M - 1;
  int ra1 = m0 + r + 64; if (ra1 > M - 1) ra1 = M - 1;
  const ushort* gA0 = A + (size_t)ra0 * D_IN + kq * 8;
  const ushort* gA1 = A + (size_t)ra1 * D_IN + kq * 8;
  const ushort* gB0 = Bt + (size_t)(n0 + r) * D_IN + kq * 8;
  const ushort* gB1 = Bt + (size_t)(n0 + r + 64) * D_IN + kq * 8;
  ushort* lA = As + t * 8;
  ushort* lB = Bs + t * 8;

  for (int k0 = 0; k0 < D_IN; k0 += BK) {
    __syncthreads();
    __builtin_amdgcn_global_load_lds((const __attribute__((address_space(1))) void*)(gA0 + k0),
                                     (__attribute__((address_space(3))) void*)lA, 16, 0, 0);
    __builtin_amdgcn_global_load_lds((const __attribute__((address_space(1))) void*)(gA1 + k0),
                                     (__attribute__((address_space(3))) void*)(lA + 64 * BK), 16, 0, 0);
    __builtin_amdgcn_global_load_lds((const __attribute__((address_space(1))) void*)(gB0 + k0),
                                     (__attribute__((address_space(3))) void*)lB, 16, 0, 0);
    __builtin_amdgcn_global_load_lds((const __attribute__((address_space(1))) void*)(gB1 + k0),
                                     (__attribute__((address_space(3))) void*)(lB + 64 * BK), 16, 0, 0);
    __syncthreads();
    short8 a[4], b[4];
#pragma unroll
    for (int i = 0; i < 4; ++i)
      a[i] = *(const short8*)&As[(wm + i * 16 + ln) * BK + qd * 8];
#pragma unroll
    for (int j = 0; j < 4; ++j)
      b[j] = *(const short8*)&Bs[(wn + j * 16 + ln) * BK + qd * 8];
#pragma unroll
    for (int i = 0; i < 4; ++i)
#pragma unroll
      for (int j = 0; j < 4; ++j)
        acc[i][j] = __builtin_amdgcn_mfma_f32_16x16x32_bf16(a[i], b[j], acc[i][j], 0, 0, 0);
  }

  // ---- C store (C/D layout: col = ln, row = qd*4 + reg) ----
#pragma unroll
  for (int i = 0; i < 4; ++i) {
#pragma unroll
    for (int reg = 0; reg < 4; ++reg) {
      int row = m0 + wm + i * 16 + qd * 4 + reg;
      if (row >= M) continue;
#pragma unroll
      for (int j = 0; j < 4; ++j)
        Cbf[(size_t)row * HC + n0 + wn + j * 16 + ln] = f2bf(acc[i][j][reg]);
    }
  }

  // ---- fused attention scores ----
  int colbase = n0 + wn;         // multiple of 64
  int h = colbase / C;
  float sa[4], da[4];
#pragma unroll
  for (int j = 0; j < 4; ++j) {
    int c = (colbase % C) + j * 16 + ln;
    sa[j] = att_s[h * C + c];
    da[j] = att_d[h * C + c];
  }
#pragma unroll
  for (int i = 0; i < 4; ++i) {
#pragma unroll
    for (int reg = 0; reg < 4; ++reg) {
      float ps = acc[i][0][reg] * sa[0] + acc[i][1][reg] * sa[1]
               + acc[i][2][reg] * sa[2] + acc[i][3][reg] * sa[3];
      float pd = acc[i][0][reg] * da[0] + acc[i][1][reg] * da[1]
               + acc[i][2][reg] * da[2] + acc[i][3][reg] * da[3];
#pragma unroll
      for (int o = 1; o < 16; o <<= 1) { ps += __shfl_xor(ps, o); pd += __shfl_xor(pd, o); }
      int row = m0 + wm + i * 16 + qd * 4 + reg;
      if (ln == 0 && row < M) {
        if (C == 64) { asrc[row * H + h] = ps; adst[row * H + h] = pd; }
        else { atomicAdd(&asrc[row * H + h], ps); atomicAdd(&adst[row * H + h], pd); }
      }
    }
  }
}

// ---------------- CSR build ------------------------------------------------
__global__ void k_hist(const int* __restrict__ ei, int E, int Etot, int* __restrict__ cnt) {
  int e = blockIdx.x * blockDim.x + threadIdx.x;
  if (e >= Etot) return;
  int d = (e < E) ? ei[E + e] : e - E;
  atomicAdd(&cnt[d], 1);
}

// single-block scan, thread-serial + shuffle (2 barriers total)
__global__ void k_scan(const int* __restrict__ cnt, int* __restrict__ rowstart, int N) {
  int tid = threadIdx.x;                 // 1024
  int T = (N + 1023) / 1024;
  int base = tid * T;
  int sum = 0;
  for (int i = 0; i < T; ++i) { int j = base + i; if (j < N) sum += cnt[j]; }
  int lane = tid & 63, w = tid >> 6;
  int v = sum;
#pragma unroll
  for (int off = 1; off < 64; off <<= 1) {
    int u = __shfl_up(v, off);
    if (lane >= off) v += u;
  }
  __shared__ int wsum[16];
  if (lane == 63) wsum[w] = v;
  __syncthreads();
  if (tid < 16) {
    int tv = wsum[tid];
#pragma unroll
    for (int off = 1; off < 16; off <<= 1) {
      int u = __shfl_up(tv, off);
      if (tid >= off) tv += u;
    }
    wsum[tid] = tv;
  }
  __syncthreads();
  int wave_prefix = (w == 0) ? 0 : wsum[w - 1];
  int run = wave_prefix + v - sum;       // exclusive prefix for this thread
  for (int i = 0; i < T; ++i) {
    int j = base + i;
    if (j < N) { rowstart[j] = run; run += cnt[j]; }
  }
  if (tid == 1023) rowstart[N] = run;
}

__global__ void k_scatter(const int* __restrict__ ei, int E, int Etot,
                          const int* __restrict__ rowstart, int* __restrict__ cursor,
                          int* __restrict__ csr_src, int* __restrict__ csr_dst) {
  int e = blockIdx.x * blockDim.x + threadIdx.x;
  if (e >= Etot) return;
  int s = (e < E) ? ei[e] : e - E;
  int d = (e < E) ? ei[E + e] : e - E;
  int pos = atomicAdd(&cursor[d], 1);
  int slot = rowstart[d] + pos;
  csr_src[slot] = s;
  csr_dst[slot] = d;
}

// -------- fused edge: exp(leaky_relu(asrc+adst)) + segment-sum (no max) ----
__global__ void k_edge(const int* __restrict__ csr_src, const int* __restrict__ csr_dst,
                       int Etot, const float* __restrict__ asrc,
                       const float* __restrict__ adst,
                       float* __restrict__ esc, float* __restrict__ den, int H) {
  int idx = blockIdx.x * blockDim.x + threadIdx.x;
  if (idx >= Etot * H) return;
  int slot = idx / H, h = idx - slot * H;
  int s = csr_src[slot], d = csr_dst[slot];
  float v = asrc[s * H + h] + adst[d * H + h];
  v = (v > 0.f) ? v : 0.2f * v;
  float ex = __expf(v);
  esc[idx] = ex;
  atomicAdd(&den[d * H + h], ex);
}

// -------- gather aggregation, 128 thr/node, LDS-staged edges ---------------
// mode 1: hout = bf16(elu(sum/den + b))   (layer 1)
// mode 2: out2[n,c] = mean_h(sum/den) + b[c]  (layer 2, fp32)
__global__ void k_agg(const int* __restrict__ rowstart, const int* __restrict__ csr_src,
                      const float* __restrict__ esc, const float* __restrict__ den,
                      const ushort* __restrict__ xp, ushort* __restrict__ hout,
                      float* __restrict__ out2, const float* __restrict__ bias,
                      int H, int mode) {
  int n = blockIdx.x;
  int tid = threadIdx.x;                 // 128
  int C = HC / H;
  int h = (tid * 4) / C;
  int beg = rowstart[n], end = rowstart[n + 1];
  int CHUNK = 128 / H;                   // 16 (H=8) or 32 (H=4)

  __shared__ int   s_src[32];
  __shared__ float s_a[128];
  __shared__ float s_out[512];

  float ax = 0.f, ay = 0.f, az = 0.f, aw = 0.f;

  for (int c0 = beg; c0 < end; c0 += CHUNK) {
    int len = end - c0; if (len > CHUNK) len = CHUNK;
    __syncthreads();
    if (tid < len) s_src[tid] = csr_src[c0 + tid];
    if (tid < len * H) s_a[tid] = esc[c0 * H + tid];
    __syncthreads();
    for (int i = 0; i < len; ++i) {
      int s = s_src[i];
      float w = s_a[i * H + h];
      ushort4 v = ((const ushort4*)xp)[(size_t)s * 128 + tid];
      ax += w * bf2f(v.x); ay += w * bf2f(v.y);
      az += w * bf2f(v.z); aw += w * bf2f(v.w);
    }
  }
  float rdn = 1.0f / (den[n * H + h] + 1e-16f);
  ax *= rdn; ay *= rdn; az *= rdn; aw *= rdn;

  if (mode == 1) {
    int hc = tid * 4;
    float v0 = ax + bias[hc], v1 = ay + bias[hc + 1];
    float v2 = az + bias[hc + 2], v3 = aw + bias[hc + 3];
    v0 = (v0 > 0.f) ? v0 : expm1f(v0);
    v1 = (v1 > 0.f) ? v1 : expm1f(v1);
    v2 = (v2 > 0.f) ? v2 : expm1f(v2);
    v3 = (v3 > 0.f) ? v3 : expm1f(v3);
    ushort4 rr = { f2bf(v0), f2bf(v1), f2bf(v2), f2bf(v3) };
    ((ushort4*)hout)[(size_t)n * 128 + tid] = rr;
  } else {
    int hc = tid * 4;
    s_out[hc] = ax; s_out[hc + 1] = ay; s_out[hc + 2] = az; s_out[hc + 3] = aw;
    __syncthreads();
    if (tid < 32) {
      for (int k = 0; k < 4; ++k) {
        int c = tid * 4 + k;
        float sum = s_out[c] + s_out[128 + c] + s_out[256 + c] + s_out[384 + c];
        out2[(size_t)n * NC2 + c] = sum * 0.25f + bias[c];
      }
    }
  }
}

// -------- CE loss: one wave per node, atomics spread over 128 slot pairs ---
__global__ void k_loss(const float* __restrict__ out, const int* __restrict__ y,
                       const int* __restrict__ msk, float* __restrict__ acc2, int N) {
  int gtid = blockIdx.x * blockDim.x + threadIdx.x;
  int wave = gtid >> 6;
  int lane = gtid & 63;
  if (wave >= N) return;
  const float* row = out + (size_t)wave * NC2;
  float v0 = row[lane], v1 = row[lane + 64];
  float mx = fmaxf(v0, v1);
#pragma unroll
  for (int o = 32; o > 0; o >>= 1) mx = fmaxf(mx, __shfl_xor(mx, o));
  float se = expf(v0 - mx) + expf(v1 - mx);
#pragma unroll
  for (int o = 32; o > 0; o >>= 1) se += __shfl_xor(se, o);
  if (lane == 0 && msk[wave] != 0) {
    float lse = mx + logf(se);
    float ce = lse - row[y[wave]];
    int slot = blockIdx.x & 127;
    atomicAdd(&acc2[slot], ce);
    atomicAdd(&acc2[128 + slot], 1.0f);
  }
}

__global__ void k_final(const float* __restrict__ acc2, float* __restrict__ out0) {
  int tid = threadIdx.x;   // 128 threads
  float ce = acc2[tid], ct = acc2[128 + tid];
#pragma unroll
  for (int o = 32; o > 0; o >>= 1) { ce += __shfl_xor(ce, o); ct += __shfl_xor(ct, o); }
  __shared__ float s[4];
  if ((tid & 63) == 0) { s[(tid >> 6) * 2] = ce; s[(tid >> 6) * 2 + 1] = ct; }
  __syncthreads();
  if (tid == 0) out0[0] = (s[0] + s[2]) / (s[1] + s[3]);
}

extern "C" void kernel_launch(void* const* d_in, const int* in_sizes, int n_in,
                              void* d_out, int out_size, void* d_ws, size_t ws_size,
                              hipStream_t stream) {
  const float* x   = (const float*)d_in[0];
  const int*   ei  = (const int*)d_in[1];
  const int*   y   = (const int*)d_in[2];
  const int*   msk = (const int*)d_in[3];
  const float* W1  = (const float*)d_in[4];
  const float* as1 = (const float*)d_in[5];
  const float* ad1 = (const float*)d_in[6];
  const float* b1  = (const float*)d_in[7];
  const float* W2  = (const float*)d_in[8];
  const float* as2 = (const float*)d_in[9];
  const float* ad2 = (const float*)d_in[10];
  const float* b2  = (const float*)d_in[11];
  float* out = (float*)d_out;

  int N = in_sizes[0] / D_IN;   // 20000
  int E = in_sizes[1] / 2;      // 100000
  int Etot = E + N;             // 120000 (self-loops appended)

  float* ws = (float*)d_ws;
  size_t NF = (size_t)N * HC;
  float* asr1 = ws;                       // N*8 (plain-written in GEMM1)
  float* adt1 = asr1 + (size_t)N * NH1;   // N*8
  // ---- zero-init region: den1, den2, asr2, adt2, acc2, cnt, cursor ----
  float* den1 = adt1 + (size_t)N * NH1;   // N*8
  float* den2 = den1 + (size_t)N * NH1;   // N*4
  float* asr2 = den2 + (size_t)N * NH2;   // N*4 (atomicAdd in GEMM2)
  float* adt2 = asr2 + (size_t)N * NH2;   // N*4
  float* acc2 = adt2 + (size_t)N * NH2;   // 256
  int*   cnt    = (int*)(acc2 + 256);     // N
  int*   cursor = cnt + N;                // N
  size_t zero_bytes = ((size_t)N * (NH1 + 3 * NH2) + 256 + 2 * (size_t)N) * sizeof(float);
  // ---- fully-written region ----
  int*   rowstart = cursor + N;           // N+1
  int*   csr_src  = rowstart + N + 1;     // Etot
  int*   csr_dst  = csr_src + Etot;       // Etot
  float* esc1 = (float*)(csr_dst + Etot); // Etot*8
  float* esc2 = esc1 + (size_t)Etot * NH1;// Etot*4
  ushort* xpbf = (ushort*)((((uintptr_t)(esc2 + (size_t)Etot * NH2)) + 15) & ~(uintptr_t)15);
  ushort* Abf = xpbf + NF;                // N*512
  ushort* Wt1 = Abf + NF;                 // 512*512
  ushort* Wt2 = Wt1 + (size_t)D_IN * HC;  // 512*512

  hipMemsetAsync(den1, 0, zero_bytes, stream);

  // weight transpose-casts (both layers)
  k_castT<<<(D_IN * HC + 255) / 256, 256, 0, stream>>>(W1, Wt1, D_IN, HC);
  k_castT<<<(D_IN * HC + 255) / 256, 256, 0, stream>>>(W2, Wt2, D_IN, HC);

  // CSR build (shared by both layers)
  k_hist<<<(Etot + 255) / 256, 256, 0, stream>>>(ei, E, Etot, cnt);
  k_scan<<<1, 1024, 0, stream>>>(cnt, rowstart, N);
  k_scatter<<<(Etot + 255) / 256, 256, 0, stream>>>(ei, E, Etot, rowstart, cursor, csr_src, csr_dst);

  dim3 ggrid(HC / BN, (N + BM - 1) / BM);

  // ---- layer 1 ----
  k_cast<<<(int)((NF / 4 + 255) / 256), 256, 0, stream>>>(x, Abf, (int)(NF / 4));
  k_gemm_bf16<NH1><<<ggrid, 256, 0, stream>>>(Abf, Wt1, xpbf, as1, ad1, asr1, adt1, N);
  k_edge<<<(Etot * NH1 + 255) / 256, 256, 0, stream>>>(csr_src, csr_dst, Etot, asr1, adt1, esc1, den1, NH1);
  k_agg<<<N, 128, 0, stream>>>(rowstart, csr_src, esc1, den1, xpbf, Abf, nullptr, b1, NH1, 1);

  // ---- layer 2 ----
  k_gemm_bf16<NH2><<<ggrid, 256, 0, stream>>>(Abf, Wt2, xpbf, as2, ad2, asr2, adt2, N);
  k_edge<<<(Etot * NH2 + 255) / 256, 256, 0, stream>>>(csr_src, csr_dst, Etot, asr2, adt2, esc2, den2, NH2);
  k_agg<<<N, 128, 0, stream>>>(rowstart, csr_src, esc2, den2, xpbf, nullptr, out + 1, b2, NH2, 2);

  // ---- epilogue: loss ----
  k_loss<<<(N * 64 + 255) / 256, 256, 0, stream>>>(out + 1, y, msk, acc2, N);
  k_final<<<1, 128, 0, stream>>>(acc2, out);
}